// Round 1
// baseline (134.886 us; speedup 1.0000x reference)
//
#include <hip/hip_runtime.h>

#define PPB 262144  // points per batch
#define NBATCH 16

// basis blades sorted by (grade, value), and the inverse map
static __device__ const int   kBits[16]  = {0,1,2,4,8,3,5,6,9,10,12,7,11,13,14,15};
static __device__ const int   kIdxOf[16] = {0,1,2,5,3,6,7,11,4,8,9,12,10,13,14,15};
static __device__ const float kRev[16]   = {1,1,1,1,1,-1,-1,-1,-1,-1,-1,-1,-1,-1,-1,1};

// One block per batch: build Cayley table T, fold motor into the 16x16
// sandwich matrix M_b with out = M_b . x  (row-major M[l][j]).
__global__ void build_sandwich(const float* __restrict__ motor, float* __restrict__ M)
{
    __shared__ float T[16][16][16];
    __shared__ float A[16][16];
    __shared__ float B[16][16];
    __shared__ float m[16], mrev[16];
    const int t = threadIdx.x;
    const int r = t >> 4, c = t & 15;
    const int b = blockIdx.x;

    if (t < 16) { float mv = motor[b * 16 + t]; m[t] = mv; mrev[t] = mv * kRev[t]; }

    #pragma unroll
    for (int k = 0; k < 16; ++k) T[r][c][k] = 0.f;
    {
        const int bi = kBits[r], bj = kBits[c];
        int swaps = 0;
        #pragma unroll
        for (int k = 0; k < 4; ++k)
            if ((bi >> k) & 1) swaps += __popc(bj & ((1 << k) - 1));
        if (!((bi & bj) & 8))                       // e3^2 = 0 (degenerate metric)
            T[r][c][kIdxOf[bi ^ bj]] = (swaps & 1) ? -1.f : 1.f;
    }
    __syncthreads();

    // A[k=r][j=c] = sum_i m[i]   * T[i][c][r]   (tmp = m * x)
    // B[l=r][k=c] = sum_j mrev[j]* T[c][j][r]   (out = tmp * mrev)
    float av = 0.f, bv = 0.f;
    #pragma unroll
    for (int i = 0; i < 16; ++i) {
        av += m[i]    * T[i][c][r];
        bv += mrev[i] * T[c][i][r];
    }
    A[r][c] = av;
    B[r][c] = bv;
    __syncthreads();

    float acc = 0.f;
    #pragma unroll
    for (int k = 0; k < 16; ++k) acc += B[r][k] * A[k][c];
    M[b * 256 + t] = acc;
}

// Apply M_b to every point. 2 points per thread, float4 everything.
__global__ __launch_bounds__(256) void apply_sandwich(
    const float4* __restrict__ x, const float* __restrict__ M,
    float4* __restrict__ out)
{
    __shared__ float4 Ms[16][4];              // row-major 16x16 matrix as float4 rows
    const int tid = threadIdx.x;
    const int b = blockIdx.y;
    if (tid < 64)
        ((float4*)Ms)[tid] = ((const float4*)(M + (size_t)b * 256))[tid];
    __syncthreads();

    const size_t p0 = (size_t)b * PPB + (size_t)blockIdx.x * 512 + tid;
    const size_t p1 = p0 + 256;

    float4 xa4[4], xb4[4], oa4[4], ob4[4];
    const float4* xp0 = x + p0 * 4;
    const float4* xp1 = x + p1 * 4;
    #pragma unroll
    for (int q = 0; q < 4; ++q) { xa4[q] = xp0[q]; xb4[q] = xp1[q]; }
    const float* xa = (const float*)xa4;
    const float* xb = (const float*)xb4;
    float* oa = (float*)oa4;
    float* ob = (float*)ob4;

    #pragma unroll
    for (int l = 0; l < 16; ++l) {
        float sa = 0.f, sb = 0.f;
        #pragma unroll
        for (int q = 0; q < 4; ++q) {
            const float4 mr = Ms[l][q];
            sa += mr.x * xa[4*q+0] + mr.y * xa[4*q+1] + mr.z * xa[4*q+2] + mr.w * xa[4*q+3];
            sb += mr.x * xb[4*q+0] + mr.y * xb[4*q+1] + mr.z * xb[4*q+2] + mr.w * xb[4*q+3];
        }
        oa[l] = sa;
        ob[l] = sb;
    }

    float4* op0 = out + p0 * 4;
    float4* op1 = out + p1 * 4;
    #pragma unroll
    for (int q = 0; q < 4; ++q) { op0[q] = oa4[q]; op1[q] = ob4[q]; }
}

extern "C" void kernel_launch(void* const* d_in, const int* in_sizes, int n_in,
                              void* d_out, int out_size, void* d_ws, size_t ws_size,
                              hipStream_t stream)
{
    const float* x     = (const float*)d_in[0];   // (16, 262144, 16) fp32
    const float* motor = (const float*)d_in[1];   // (16, 16) fp32
    float* out = (float*)d_out;
    float* M   = (float*)d_ws;                    // 16 * 256 floats = 16 KB

    build_sandwich<<<NBATCH, 256, 0, stream>>>(motor, M);

    dim3 grid(PPB / 512, NBATCH);
    apply_sandwich<<<grid, 256, 0, stream>>>((const float4*)x, M, (float4*)out);
}

// Round 2
// 102.876 us; speedup vs baseline: 1.3112x; 1.3112x over previous
//
#include <hip/hip_runtime.h>

#define PPB 262144  // points per batch
#define NBATCH 16
#define TPB 256
#define NPT 8       // float4-tasks per thread

// basis blades sorted by (grade, value), and the inverse map
static __device__ const int   kBits[16]  = {0,1,2,4,8,3,5,6,9,10,12,7,11,13,14,15};
static __device__ const int   kIdxOf[16] = {0,1,2,5,3,6,7,11,4,8,9,12,10,13,14,15};
static __device__ const float kRev[16]   = {1,1,1,1,1,-1,-1,-1,-1,-1,-1,-1,-1,-1,-1,1};

// One block per batch: build Cayley table T, fold motor into the 16x16
// sandwich matrix M_b with out = M_b . x  (row-major M[l][j]).
__global__ void build_sandwich(const float* __restrict__ motor, float* __restrict__ M)
{
    __shared__ float T[16][16][16];
    __shared__ float A[16][16];
    __shared__ float B[16][16];
    __shared__ float m[16], mrev[16];
    const int t = threadIdx.x;
    const int r = t >> 4, c = t & 15;
    const int b = blockIdx.x;

    if (t < 16) { float mv = motor[b * 16 + t]; m[t] = mv; mrev[t] = mv * kRev[t]; }

    #pragma unroll
    for (int k = 0; k < 16; ++k) T[r][c][k] = 0.f;
    {
        const int bi = kBits[r], bj = kBits[c];
        int swaps = 0;
        #pragma unroll
        for (int k = 0; k < 4; ++k)
            if ((bi >> k) & 1) swaps += __popc(bj & ((1 << k) - 1));
        if (!((bi & bj) & 8))                       // e3^2 = 0 (degenerate metric)
            T[r][c][kIdxOf[bi ^ bj]] = (swaps & 1) ? -1.f : 1.f;
    }
    __syncthreads();

    // A[k=r][j=c] = sum_i m[i]   * T[i][c][r]   (tmp = m * x)
    // B[l=r][k=c] = sum_j mrev[j]* T[c][j][r]   (out = tmp * mrev)
    float av = 0.f, bv = 0.f;
    #pragma unroll
    for (int i = 0; i < 16; ++i) {
        av += m[i]    * T[i][c][r];
        bv += mrev[i] * T[c][i][r];
    }
    A[r][c] = av;
    B[r][c] = bv;
    __syncthreads();

    float acc = 0.f;
    #pragma unroll
    for (int k = 0; k < 16; ++k) acc += B[r][k] * A[k][c];
    M[b * 256 + t] = acc;
}

__device__ inline float4 shfl_xor4(float4 v, int mask) {
    float4 r;
    r.x = __shfl_xor(v.x, mask);
    r.y = __shfl_xor(v.y, mask);
    r.z = __shfl_xor(v.z, mask);
    r.w = __shfl_xor(v.w, mask);
    return r;
}

__device__ inline float dot4(float4 a, float4 b) {
    return a.x * b.x + a.y * b.y + a.z * b.z + a.w * b.w;
}

// Quad-cooperative apply: each lane owns ONE float4 (quad q = lane&3 of
// point g/4). Loads/stores are fully contiguous per wave instruction.
// M rows for this lane's output quad live in registers, column-quads
// pre-rotated by (q^s) so all inner indexing is compile-time constant.
__global__ __launch_bounds__(TPB) void apply_sandwich(
    const float4* __restrict__ x, const float* __restrict__ M,
    float4* __restrict__ out)
{
    const int t = threadIdx.x;
    const int q = t & 3;
    const int b = blockIdx.y;

    const float* Mb = M + (size_t)b * 256;
    float4 m0_0, m0_1, m0_2, m0_3;
    float4 m1_0, m1_1, m1_2, m1_3;
    float4 m2_0, m2_1, m2_2, m2_3;
    float4 m3_0, m3_1, m3_2, m3_3;
    {
        const int r0 = 4 * q;
        m0_0 = *(const float4*)(Mb + (r0 + 0) * 16 + 4 * (q ^ 0));
        m0_1 = *(const float4*)(Mb + (r0 + 0) * 16 + 4 * (q ^ 1));
        m0_2 = *(const float4*)(Mb + (r0 + 0) * 16 + 4 * (q ^ 2));
        m0_3 = *(const float4*)(Mb + (r0 + 0) * 16 + 4 * (q ^ 3));
        m1_0 = *(const float4*)(Mb + (r0 + 1) * 16 + 4 * (q ^ 0));
        m1_1 = *(const float4*)(Mb + (r0 + 1) * 16 + 4 * (q ^ 1));
        m1_2 = *(const float4*)(Mb + (r0 + 1) * 16 + 4 * (q ^ 2));
        m1_3 = *(const float4*)(Mb + (r0 + 1) * 16 + 4 * (q ^ 3));
        m2_0 = *(const float4*)(Mb + (r0 + 2) * 16 + 4 * (q ^ 0));
        m2_1 = *(const float4*)(Mb + (r0 + 2) * 16 + 4 * (q ^ 1));
        m2_2 = *(const float4*)(Mb + (r0 + 2) * 16 + 4 * (q ^ 2));
        m2_3 = *(const float4*)(Mb + (r0 + 2) * 16 + 4 * (q ^ 3));
        m3_0 = *(const float4*)(Mb + (r0 + 3) * 16 + 4 * (q ^ 0));
        m3_1 = *(const float4*)(Mb + (r0 + 3) * 16 + 4 * (q ^ 1));
        m3_2 = *(const float4*)(Mb + (r0 + 3) * 16 + 4 * (q ^ 2));
        m3_3 = *(const float4*)(Mb + (r0 + 3) * 16 + 4 * (q ^ 3));
    }

    const size_t base = (size_t)b * (PPB * 4) + (size_t)blockIdx.x * (TPB * NPT) + t;

    #pragma unroll
    for (int k = 0; k < NPT; ++k) {
        const size_t g = base + (size_t)k * TPB;
        const float4 x0 = x[g];                 // own quad (q^0)
        const float4 x1 = shfl_xor4(x0, 1);     // quad q^1 of same point
        const float4 x2 = shfl_xor4(x0, 2);     // quad q^2
        const float4 x3 = shfl_xor4(x0, 3);     // quad q^3

        float4 acc;
        acc.x = dot4(m0_0, x0) + dot4(m0_1, x1) + dot4(m0_2, x2) + dot4(m0_3, x3);
        acc.y = dot4(m1_0, x0) + dot4(m1_1, x1) + dot4(m1_2, x2) + dot4(m1_3, x3);
        acc.z = dot4(m2_0, x0) + dot4(m2_1, x1) + dot4(m2_2, x2) + dot4(m2_3, x3);
        acc.w = dot4(m3_0, x0) + dot4(m3_1, x1) + dot4(m3_2, x2) + dot4(m3_3, x3);

        out[g] = acc;
    }
}

extern "C" void kernel_launch(void* const* d_in, const int* in_sizes, int n_in,
                              void* d_out, int out_size, void* d_ws, size_t ws_size,
                              hipStream_t stream)
{
    const float* x     = (const float*)d_in[0];   // (16, 262144, 16) fp32
    const float* motor = (const float*)d_in[1];   // (16, 16) fp32
    float* out = (float*)d_out;
    float* M   = (float*)d_ws;                    // 16 * 256 floats = 16 KB

    build_sandwich<<<NBATCH, 256, 0, stream>>>(motor, M);

    dim3 grid(PPB * 4 / (TPB * NPT), NBATCH);     // (512, 16)
    apply_sandwich<<<grid, TPB, 0, stream>>>((const float4*)x, M, (float4*)out);
}

// Round 4
// 96.616 us; speedup vs baseline: 1.3961x; 1.0648x over previous
//
#include <hip/hip_runtime.h>

#define PPB 262144  // points per batch
#define NBATCH 16
#define TPB 256
#define NPT 8       // float4-tasks per thread

typedef float f32x4 __attribute__((ext_vector_type(4)));

// basis blades sorted by (grade, value), and the inverse map
static __device__ const int   kBits[16]  = {0,1,2,4,8,3,5,6,9,10,12,7,11,13,14,15};
static __device__ const int   kIdxOf[16] = {0,1,2,5,3,6,7,11,4,8,9,12,10,13,14,15};
static __device__ const float kRev[16]   = {1,1,1,1,1,-1,-1,-1,-1,-1,-1,-1,-1,-1,-1,1};

// One block per batch: build Cayley table T, fold motor into the 16x16
// sandwich matrix M_b with out = M_b . x  (row-major M[l][j]).
__global__ void build_sandwich(const float* __restrict__ motor, float* __restrict__ M)
{
    __shared__ float T[16][16][16];
    __shared__ float A[16][16];
    __shared__ float B[16][16];
    __shared__ float m[16], mrev[16];
    const int t = threadIdx.x;
    const int r = t >> 4, c = t & 15;
    const int b = blockIdx.x;

    if (t < 16) { float mv = motor[b * 16 + t]; m[t] = mv; mrev[t] = mv * kRev[t]; }

    #pragma unroll
    for (int k = 0; k < 16; ++k) T[r][c][k] = 0.f;
    {
        const int bi = kBits[r], bj = kBits[c];
        int swaps = 0;
        #pragma unroll
        for (int k = 0; k < 4; ++k)
            if ((bi >> k) & 1) swaps += __popc(bj & ((1 << k) - 1));
        if (!((bi & bj) & 8))                       // e3^2 = 0 (degenerate metric)
            T[r][c][kIdxOf[bi ^ bj]] = (swaps & 1) ? -1.f : 1.f;
    }
    __syncthreads();

    // A[k=r][j=c] = sum_i m[i]   * T[i][c][r]   (tmp = m * x)
    // B[l=r][k=c] = sum_j mrev[j]* T[c][j][r]   (out = tmp * mrev)
    float av = 0.f, bv = 0.f;
    #pragma unroll
    for (int i = 0; i < 16; ++i) {
        av += m[i]    * T[i][c][r];
        bv += mrev[i] * T[c][i][r];
    }
    A[r][c] = av;
    B[r][c] = bv;
    __syncthreads();

    float acc = 0.f;
    #pragma unroll
    for (int k = 0; k < 16; ++k) acc += B[r][k] * A[k][c];
    M[b * 256 + t] = acc;
}

// DPP quad_perm: VALU-pipe intra-quad lane swap (replaces ds_swizzle shuffles).
// xor1 -> [1,0,3,2] = 0xB1, xor2 -> [2,3,0,1] = 0x4E, xor3 -> [3,2,1,0] = 0x1B
template<int CTRL>
__device__ inline float dpp1(float v) {
    int i = __float_as_int(v);
    i = __builtin_amdgcn_update_dpp(0, i, CTRL, 0xF, 0xF, true);
    return __int_as_float(i);
}
template<int CTRL>
__device__ inline float4 dpp4(float4 v) {
    float4 r;
    r.x = dpp1<CTRL>(v.x);
    r.y = dpp1<CTRL>(v.y);
    r.z = dpp1<CTRL>(v.z);
    r.w = dpp1<CTRL>(v.w);
    return r;
}

__device__ inline float dot4(float4 a, float4 b) {
    return a.x * b.x + a.y * b.y + a.z * b.z + a.w * b.w;
}

// Quad-cooperative apply: each lane owns ONE float4 (quad q = lane&3 of
// point g/4). Loads/stores are fully contiguous per wave instruction.
// M rows for this lane's output quad live in registers, column-quads
// pre-rotated by (q^s) so all inner indexing is compile-time constant.
// Cross-quad exchange via DPP quad_perm (zero DS-pipe ops in this kernel).
__global__ __launch_bounds__(TPB) void apply_sandwich(
    const f32x4* __restrict__ x, const float* __restrict__ M,
    f32x4* __restrict__ out)
{
    const int t = threadIdx.x;
    const int q = t & 3;
    const int b = blockIdx.y;

    const float* Mb = M + (size_t)b * 256;
    float4 m0_0, m0_1, m0_2, m0_3;
    float4 m1_0, m1_1, m1_2, m1_3;
    float4 m2_0, m2_1, m2_2, m2_3;
    float4 m3_0, m3_1, m3_2, m3_3;
    {
        const int r0 = 4 * q;
        m0_0 = *(const float4*)(Mb + (r0 + 0) * 16 + 4 * (q ^ 0));
        m0_1 = *(const float4*)(Mb + (r0 + 0) * 16 + 4 * (q ^ 1));
        m0_2 = *(const float4*)(Mb + (r0 + 0) * 16 + 4 * (q ^ 2));
        m0_3 = *(const float4*)(Mb + (r0 + 0) * 16 + 4 * (q ^ 3));
        m1_0 = *(const float4*)(Mb + (r0 + 1) * 16 + 4 * (q ^ 0));
        m1_1 = *(const float4*)(Mb + (r0 + 1) * 16 + 4 * (q ^ 1));
        m1_2 = *(const float4*)(Mb + (r0 + 1) * 16 + 4 * (q ^ 2));
        m1_3 = *(const float4*)(Mb + (r0 + 1) * 16 + 4 * (q ^ 3));
        m2_0 = *(const float4*)(Mb + (r0 + 2) * 16 + 4 * (q ^ 0));
        m2_1 = *(const float4*)(Mb + (r0 + 2) * 16 + 4 * (q ^ 1));
        m2_2 = *(const float4*)(Mb + (r0 + 2) * 16 + 4 * (q ^ 2));
        m2_3 = *(const float4*)(Mb + (r0 + 2) * 16 + 4 * (q ^ 3));
        m3_0 = *(const float4*)(Mb + (r0 + 3) * 16 + 4 * (q ^ 0));
        m3_1 = *(const float4*)(Mb + (r0 + 3) * 16 + 4 * (q ^ 1));
        m3_2 = *(const float4*)(Mb + (r0 + 3) * 16 + 4 * (q ^ 2));
        m3_3 = *(const float4*)(Mb + (r0 + 3) * 16 + 4 * (q ^ 3));
    }

    const size_t base = (size_t)b * (PPB * 4) + (size_t)blockIdx.x * (TPB * NPT) + t;

    #pragma unroll
    for (int k = 0; k < NPT; ++k) {
        const size_t g = base + (size_t)k * TPB;
        const f32x4 xv = __builtin_nontemporal_load(&x[g]);   // own quad (q^0)
        float4 x0;
        x0.x = xv.x; x0.y = xv.y; x0.z = xv.z; x0.w = xv.w;
        const float4 x1 = dpp4<0xB1>(x0);                     // quad q^1 of same point
        const float4 x2 = dpp4<0x4E>(x0);                     // quad q^2
        const float4 x3 = dpp4<0x1B>(x0);                     // quad q^3

        f32x4 acc;
        acc.x = dot4(m0_0, x0) + dot4(m0_1, x1) + dot4(m0_2, x2) + dot4(m0_3, x3);
        acc.y = dot4(m1_0, x0) + dot4(m1_1, x1) + dot4(m1_2, x2) + dot4(m1_3, x3);
        acc.z = dot4(m2_0, x0) + dot4(m2_1, x1) + dot4(m2_2, x2) + dot4(m2_3, x3);
        acc.w = dot4(m3_0, x0) + dot4(m3_1, x1) + dot4(m3_2, x2) + dot4(m3_3, x3);

        __builtin_nontemporal_store(acc, &out[g]);
    }
}

extern "C" void kernel_launch(void* const* d_in, const int* in_sizes, int n_in,
                              void* d_out, int out_size, void* d_ws, size_t ws_size,
                              hipStream_t stream)
{
    const float* x     = (const float*)d_in[0];   // (16, 262144, 16) fp32
    const float* motor = (const float*)d_in[1];   // (16, 16) fp32
    float* out = (float*)d_out;
    float* M   = (float*)d_ws;                    // 16 * 256 floats = 16 KB

    build_sandwich<<<NBATCH, 256, 0, stream>>>(motor, M);

    dim3 grid(PPB * 4 / (TPB * NPT), NBATCH);     // (512, 16)
    apply_sandwich<<<grid, TPB, 0, stream>>>((const f32x4*)x, M, (f32x4*)out);
}

// Round 5
// 90.012 us; speedup vs baseline: 1.4985x; 1.0734x over previous
//
#include <hip/hip_runtime.h>

#define PPB 262144  // points per batch
#define NBATCH 16
#define TPB 256
#define NPT 8       // float4-tasks per thread

typedef float f32x4 __attribute__((ext_vector_type(4)));

// blade bits of grade-sorted index i, and inverse, packed as 16 nibbles
#define PACK_BITS  0xFEDB7CA965384210ull  // kBits  = {0,1,2,4,8,3,5,6,9,10,12,7,11,13,14,15}
#define PACK_IDXOF 0xFEDAC984B7635210ull  // kIdxOf = {0,1,2,5,3,6,7,11,4,8,9,12,10,13,14,15}
#define REV_NEG_MASK 0x7FE0               // indices 5..14 have reverse sign -1

__device__ __forceinline__ int bits_of(int i) { return (int)((PACK_BITS  >> (4 * i)) & 15ull); }
__device__ __forceinline__ int idx_of (int b) { return (int)((PACK_IDXOF >> (4 * b)) & 15ull); }

// reordering-swap parity sign for left-blade bits bl, right-blade bits br
__device__ __forceinline__ float sign_of(int bl, int br) {
    int swaps = 0;
    #pragma unroll
    for (int k = 0; k < 4; ++k)
        if ((bl >> k) & 1) swaps += __popc(br & ((1 << k) - 1));
    return (swaps & 1) ? -1.f : 1.f;
}

// DPP quad_perm: VALU-pipe intra-quad lane swap.
// xor1 -> [1,0,3,2] = 0xB1, xor2 -> [2,3,0,1] = 0x4E, xor3 -> [3,2,1,0] = 0x1B
template<int CTRL>
__device__ inline float dpp1(float v) {
    int i = __float_as_int(v);
    i = __builtin_amdgcn_update_dpp(0, i, CTRL, 0xF, 0xF, true);
    return __int_as_float(i);
}
template<int CTRL>
__device__ inline float4 dpp4(float4 v) {
    float4 r;
    r.x = dpp1<CTRL>(v.x);
    r.y = dpp1<CTRL>(v.y);
    r.z = dpp1<CTRL>(v.z);
    r.w = dpp1<CTRL>(v.w);
    return r;
}

__device__ inline float dot4(float4 a, float4 b) {
    return a.x * b.x + a.y * b.y + a.z * b.z + a.w * b.w;
}

// Single fused kernel. Preamble: analytically fold motor -> 16x16 sandwich
// matrix M (out = M.x) in LDS (no Cayley table, no second kernel). Main loop:
// quad-cooperative streaming apply, fully contiguous float4 loads/stores,
// cross-quad exchange via DPP quad_perm.
__global__ __launch_bounds__(TPB) void sandwich_fused(
    const f32x4* __restrict__ x, const float* __restrict__ motor,
    f32x4* __restrict__ out)
{
    __shared__ float mS[16], mrevS[16];
    __shared__ float A[16][16];
    __shared__ float B[16][16];
    __shared__ __align__(16) float Ms[16][16];

    const int t = threadIdx.x;
    const int q = t & 3;
    const int b = blockIdx.y;
    const int r = t >> 4, c = t & 15;

    if (t < 16) {
        float mv = motor[b * 16 + t];
        mS[t] = mv;
        mrevS[t] = ((REV_NEG_MASK >> t) & 1) ? -mv : mv;
    }
    __syncthreads();

    // A[k][j] = sum_i m_i T[i][j][k]   -> exactly one i: bits_i = bk^bj
    // B[l][k] = sum_j mrev_j T[k][j][l] -> exactly one j: bits_j = bk^bl
    {
        const int br = bits_of(r), bc = bits_of(c);
        const int bx = br ^ bc;          // the "other" operand's blade bits
        const int ii = idx_of(bx);
        const bool dead = ((bx & bc) & 8) != 0;  // degenerate e3^2 = 0
        A[r][c] = dead ? 0.f : sign_of(bx, bc) * mS[ii];    // left=i, right=j(=c)
        B[r][c] = dead ? 0.f : sign_of(bc, bx) * mrevS[ii]; // left=k(=c), right=j
    }
    __syncthreads();

    {
        float acc = 0.f;
        #pragma unroll
        for (int k = 0; k < 16; ++k) acc += B[r][k] * A[k][c];
        Ms[r][c] = acc;
    }
    __syncthreads();

    // hoist this lane's 4 output rows (col-quads pre-rotated by q^s) to regs
    const int r0 = 4 * q;
    const float4 m0_0 = *(const float4*)&Ms[r0 + 0][4 * (q ^ 0)];
    const float4 m0_1 = *(const float4*)&Ms[r0 + 0][4 * (q ^ 1)];
    const float4 m0_2 = *(const float4*)&Ms[r0 + 0][4 * (q ^ 2)];
    const float4 m0_3 = *(const float4*)&Ms[r0 + 0][4 * (q ^ 3)];
    const float4 m1_0 = *(const float4*)&Ms[r0 + 1][4 * (q ^ 0)];
    const float4 m1_1 = *(const float4*)&Ms[r0 + 1][4 * (q ^ 1)];
    const float4 m1_2 = *(const float4*)&Ms[r0 + 1][4 * (q ^ 2)];
    const float4 m1_3 = *(const float4*)&Ms[r0 + 1][4 * (q ^ 3)];
    const float4 m2_0 = *(const float4*)&Ms[r0 + 2][4 * (q ^ 0)];
    const float4 m2_1 = *(const float4*)&Ms[r0 + 2][4 * (q ^ 1)];
    const float4 m2_2 = *(const float4*)&Ms[r0 + 2][4 * (q ^ 2)];
    const float4 m2_3 = *(const float4*)&Ms[r0 + 2][4 * (q ^ 3)];
    const float4 m3_0 = *(const float4*)&Ms[r0 + 3][4 * (q ^ 0)];
    const float4 m3_1 = *(const float4*)&Ms[r0 + 3][4 * (q ^ 1)];
    const float4 m3_2 = *(const float4*)&Ms[r0 + 3][4 * (q ^ 2)];
    const float4 m3_3 = *(const float4*)&Ms[r0 + 3][4 * (q ^ 3)];

    const size_t base = (size_t)b * (PPB * 4) + (size_t)blockIdx.x * (TPB * NPT) + t;

    #pragma unroll
    for (int k = 0; k < NPT; ++k) {
        const size_t g = base + (size_t)k * TPB;
        const f32x4 xv = __builtin_nontemporal_load(&x[g]);   // own quad (q^0)
        float4 x0;
        x0.x = xv.x; x0.y = xv.y; x0.z = xv.z; x0.w = xv.w;
        const float4 x1 = dpp4<0xB1>(x0);                     // quad q^1 of same point
        const float4 x2 = dpp4<0x4E>(x0);                     // quad q^2
        const float4 x3 = dpp4<0x1B>(x0);                     // quad q^3

        f32x4 acc;
        acc.x = dot4(m0_0, x0) + dot4(m0_1, x1) + dot4(m0_2, x2) + dot4(m0_3, x3);
        acc.y = dot4(m1_0, x0) + dot4(m1_1, x1) + dot4(m1_2, x2) + dot4(m1_3, x3);
        acc.z = dot4(m2_0, x0) + dot4(m2_1, x1) + dot4(m2_2, x2) + dot4(m2_3, x3);
        acc.w = dot4(m3_0, x0) + dot4(m3_1, x1) + dot4(m3_2, x2) + dot4(m3_3, x3);

        __builtin_nontemporal_store(acc, &out[g]);
    }
}

extern "C" void kernel_launch(void* const* d_in, const int* in_sizes, int n_in,
                              void* d_out, int out_size, void* d_ws, size_t ws_size,
                              hipStream_t stream)
{
    const float* x     = (const float*)d_in[0];   // (16, 262144, 16) fp32
    const float* motor = (const float*)d_in[1];   // (16, 16) fp32
    float* out = (float*)d_out;

    dim3 grid(PPB * 4 / (TPB * NPT), NBATCH);     // (512, 16)
    sandwich_fused<<<grid, TPB, 0, stream>>>((const f32x4*)x, motor, (f32x4*)out);
}